// Round 7
// baseline (396.840 us; speedup 1.0000x reference)
//
#include <hip/hip_runtime.h>
#include <hip/hip_bf16.h>

#define NN 100000
#define NE 1600000
#define ET (NE + NN)
#define NB 391          // buckets of 256 dst nodes
#define CAP 5120        // slots/bucket (mean 4352, +12 sigma)
#define BST 16          // bcnt pad: 64B per counter

typedef __hip_bfloat16 bf16;

__device__ __forceinline__ float bf2f(bf16 v){ return __bfloat162float(v); }
__device__ __forceinline__ unsigned short bfbits(float v){
    bf16 b = __float2bfloat16(v);
    return *(unsigned short*)&b;
}

// ---------------- CSR build: bin by dst>>8 ----------------
__global__ void __launch_bounds__(256) k_bin(const int* __restrict__ src,
        const int* __restrict__ dst, int* __restrict__ bcnt,
        int* __restrict__ binbuf){
    __shared__ int cnt[NB];
    __shared__ int cur[NB];
    int t = threadIdx.x;
    for(int i=t;i<NB;i+=256) cnt[i]=0;
    __syncthreads();
    int e0 = blockIdx.x*2048;
    #pragma unroll
    for(int k=0;k<8;k++){
        int e = e0 + k*256 + t;
        if(e < ET){ int d = (e < NE) ? dst[e] : (e - NE); atomicAdd(&cnt[d>>8], 1); }
    }
    __syncthreads();
    for(int i=t;i<NB;i+=256){ int c=cnt[i]; cur[i] = c ? atomicAdd(&bcnt[i*BST], c) : 0; }
    __syncthreads();
    #pragma unroll
    for(int k=0;k<8;k++){
        int e = e0 + k*256 + t;
        if(e < ET){
            int s, d;
            if(e < NE){ s = src[e]; d = dst[e]; } else { s = e - NE; d = s; }
            int b = d >> 8;
            int pos = atomicAdd(&cur[b], 1);
            if(pos < CAP) binbuf[b*CAP + pos] = (s << 8) | (d & 255);
        }
    }
}

// ---------------- CSR build: per-bucket dense build (base prefix fused) ----------------
__global__ void __launch_bounds__(256) k_build(const int* __restrict__ bcnt,
        const int* __restrict__ binbuf, int* __restrict__ edge_src,
        int* __restrict__ rowst, int* __restrict__ deg){
    __shared__ int lsrc[CAP];
    __shared__ int ldeg[256], lscan[256], lcur[256], red[256];
    int b = blockIdx.x, t = threadIdx.x;
    int cnt = min(bcnt[b*BST], CAP);
    int part = 0;
    for(int i=t;i<b;i+=256) part += min(bcnt[i*BST], CAP);
    red[t] = part; __syncthreads();
    for(int off=128; off>=1; off>>=1){ if(t<off) red[t]+=red[t+off]; __syncthreads(); }
    int base = red[0];
    __syncthreads();
    ldeg[t] = 0; __syncthreads();
    const int* bb = binbuf + b*CAP;
    for(int i=t;i<cnt;i+=256) atomicAdd(&ldeg[bb[i] & 255], 1);
    __syncthreads();
    int dv = ldeg[t]; lscan[t] = dv; __syncthreads();
    for(int off=1; off<256; off<<=1){
        int u = (t>=off) ? lscan[t-off] : 0;
        __syncthreads(); lscan[t] += u; __syncthreads();
    }
    int excl = lscan[t] - dv; lcur[t] = excl;
    int node = b*256 + t;
    if(node < NN){ rowst[node] = base + excl; deg[node] = dv; }
    __syncthreads();
    for(int i=t;i<cnt;i+=256){
        int ent = bb[i];
        int pos = atomicAdd(&lcur[ent & 255], 1);
        lsrc[pos] = ent >> 8;
    }
    __syncthreads();
    for(int i=t;i<cnt;i+=256) edge_src[base+i] = lsrc[i];
}

// ---------------- h = x@W, s_src, s_dst ----------------
// wave per 4 nodes per iteration: 4 independent load+FMA chains (MLP/ILP x4).
// NN % 4 == 0, so every group of 4 is full.

template<int FPIN>
__global__ void __launch_bounds__(256) k_gemm(const void* __restrict__ xin,
        const float* __restrict__ W, const float* __restrict__ avs,
        const float* __restrict__ avd, bf16* __restrict__ hb,
        float* __restrict__ ssrc, float* __restrict__ sdst){
    int tid = threadIdx.x, wave = tid>>6, lane = tid&63;
    float Wreg[64];
    #pragma unroll
    for(int k=0;k<64;k++) Wreg[k] = W[k*64 + lane];
    float as = avs[lane], ad = avd[lane];
    int gw = blockIdx.x*4 + wave;               // global wave id (4096 waves)
    int stride = gridDim.x*4*4;                 // nodes per sweep
    for(int n0 = gw*4; n0 < NN; n0 += stride){
        float c0[4] = {0.f,0.f,0.f,0.f};
        float c1[4] = {0.f,0.f,0.f,0.f};
        float c2[4] = {0.f,0.f,0.f,0.f};
        float c3[4] = {0.f,0.f,0.f,0.f};
        if(FPIN){
            const float4* xr0 = (const float4*)((const float*)xin + (size_t)(n0+0)*64);
            const float4* xr1 = (const float4*)((const float*)xin + (size_t)(n0+1)*64);
            const float4* xr2 = (const float4*)((const float*)xin + (size_t)(n0+2)*64);
            const float4* xr3 = (const float4*)((const float*)xin + (size_t)(n0+3)*64);
            #pragma unroll
            for(int q=0;q<16;q++){
                float4 x0 = xr0[q], x1 = xr1[q], x2 = xr2[q], x3 = xr3[q];
                float w0 = Wreg[4*q+0], w1 = Wreg[4*q+1], w2 = Wreg[4*q+2], w3 = Wreg[4*q+3];
                c0[0] += x0.x*w0; c0[1] += x0.y*w1; c0[2] += x0.z*w2; c0[3] += x0.w*w3;
                c1[0] += x1.x*w0; c1[1] += x1.y*w1; c1[2] += x1.z*w2; c1[3] += x1.w*w3;
                c2[0] += x2.x*w0; c2[1] += x2.y*w1; c2[2] += x2.z*w2; c2[3] += x2.w*w3;
                c3[0] += x3.x*w0; c3[1] += x3.y*w1; c3[2] += x3.z*w2; c3[3] += x3.w*w3;
            }
        } else {
            const uint4* xr0 = (const uint4*)((const bf16*)xin + (size_t)(n0+0)*64);
            const uint4* xr1 = (const uint4*)((const bf16*)xin + (size_t)(n0+1)*64);
            const uint4* xr2 = (const uint4*)((const bf16*)xin + (size_t)(n0+2)*64);
            const uint4* xr3 = (const uint4*)((const bf16*)xin + (size_t)(n0+3)*64);
            #pragma unroll
            for(int q=0;q<8;q++){
                uint4 p0 = xr0[q], p1 = xr1[q], p2 = xr2[q], p3 = xr3[q];
                #pragma unroll
                for(int hh=0;hh<2;hh++){
                    float w0 = Wreg[8*q+4*hh+0], w1 = Wreg[8*q+4*hh+1];
                    float w2 = Wreg[8*q+4*hh+2], w3 = Wreg[8*q+4*hh+3];
                    unsigned u0 = hh ? p0.z : p0.x, v0 = hh ? p0.w : p0.y;
                    unsigned u1 = hh ? p1.z : p1.x, v1 = hh ? p1.w : p1.y;
                    unsigned u2 = hh ? p2.z : p2.x, v2 = hh ? p2.w : p2.y;
                    unsigned u3 = hh ? p3.z : p3.x, v3 = hh ? p3.w : p3.y;
                    c0[0] += __uint_as_float(u0<<16)*w0; c0[1] += __uint_as_float(u0&0xffff0000u)*w1;
                    c0[2] += __uint_as_float(v0<<16)*w2; c0[3] += __uint_as_float(v0&0xffff0000u)*w3;
                    c1[0] += __uint_as_float(u1<<16)*w0; c1[1] += __uint_as_float(u1&0xffff0000u)*w1;
                    c1[2] += __uint_as_float(v1<<16)*w2; c1[3] += __uint_as_float(v1&0xffff0000u)*w3;
                    c2[0] += __uint_as_float(u2<<16)*w0; c2[1] += __uint_as_float(u2&0xffff0000u)*w1;
                    c2[2] += __uint_as_float(v2<<16)*w2; c2[3] += __uint_as_float(v2&0xffff0000u)*w3;
                    c3[0] += __uint_as_float(u3<<16)*w0; c3[1] += __uint_as_float(u3&0xffff0000u)*w1;
                    c3[2] += __uint_as_float(v3<<16)*w2; c3[3] += __uint_as_float(v3&0xffff0000u)*w3;
                }
            }
        }
        float a0 = (c0[0]+c0[1]) + (c0[2]+c0[3]);
        float a1 = (c1[0]+c1[1]) + (c1[2]+c1[3]);
        float a2 = (c2[0]+c2[1]) + (c2[2]+c2[3]);
        float a3 = (c3[0]+c3[1]) + (c3[2]+c3[3]);
        hb[(size_t)(n0+0)*64 + lane] = __float2bfloat16(a0);
        hb[(size_t)(n0+1)*64 + lane] = __float2bfloat16(a1);
        hb[(size_t)(n0+2)*64 + lane] = __float2bfloat16(a2);
        hb[(size_t)(n0+3)*64 + lane] = __float2bfloat16(a3);
        float t0s = a0*as, t0d = a0*ad;
        float t1s = a1*as, t1d = a1*ad;
        float t2s = a2*as, t2d = a2*ad;
        float t3s = a3*as, t3d = a3*ad;
        #pragma unroll
        for(int m=32;m>=1;m>>=1){
            t0s += __shfl_xor(t0s,m); t0d += __shfl_xor(t0d,m);
            t1s += __shfl_xor(t1s,m); t1d += __shfl_xor(t1d,m);
            t2s += __shfl_xor(t2s,m); t2d += __shfl_xor(t2d,m);
            t3s += __shfl_xor(t3s,m); t3d += __shfl_xor(t3d,m);
        }
        if(lane==0){
            ssrc[n0+0] = t0s; sdst[n0+0] = t0d;
            ssrc[n0+1] = t1s; sdst[n0+1] = t1d;
            ssrc[n0+2] = t2s; sdst[n0+2] = t2d;
            ssrc[n0+3] = t3s; sdst[n0+3] = t3d;
        }
    }
}

// ---------------- attention + aggregation ----------------
// wave per dst node; gather vectorized: uint2/lane = 4 rows (512B) per iteration.

template<int LAYER>
__global__ void __launch_bounds__(256) k_agg(
        const int* __restrict__ rowst, const int* __restrict__ deg,
        const int* __restrict__ edge_src,
        const float* __restrict__ ssrc, const float* __restrict__ sdst,
        const bf16* __restrict__ hb,
        const float* __restrict__ bias, const float* __restrict__ Wl,
        const float* __restrict__ bl,
        bf16* __restrict__ out1b, float* __restrict__ outF){
    int wid  = (blockIdx.x*256 + threadIdx.x) >> 6;
    int lane = threadIdx.x & 63;
    if(wid >= NN) return;
    int rs = rowst[wid];
    int d  = deg[wid];
    float sd = sdst[wid];
    int grp = lane >> 4;
    int ch  = lane & 15;                 // channel chunk: bf16 channels ch*4 .. ch*4+3
    float a0=0.f, a1=0.f, a2=0.f, a3=0.f;

    if(d <= 64){
        int s = 0; float e = -1e30f;
        if(lane < d){
            s = edge_src[rs + lane];
            float t = ssrc[s] + sd;
            e = fmaxf(t, 0.2f*t);        // leaky_relu
        }
        float mx = e;
        #pragma unroll
        for(int m=32;m>=1;m>>=1) mx = fmaxf(mx, __shfl_xor(mx,m));
        float pr = (lane < d) ? __expf(e - mx) : 0.f;
        float sm = pr;
        #pragma unroll
        for(int m=32;m>=1;m>>=1) sm += __shfl_xor(sm,m);
        float alpha = pr * (1.0f/(sm + 1e-16f));
        for(int i0=0; i0<d; i0+=4){
            int r  = i0 + grp;
            int rr = (r < d) ? r : 0;
            float a = __shfl(alpha, rr);
            int  sj = __shfl(s, rr);
            if(r >= d) a = 0.f;
            uint2 pk = ((const uint2*)(hb + ((size_t)sj<<6)))[ch];
            a0 += a*__uint_as_float(pk.x<<16);
            a1 += a*__uint_as_float(pk.x&0xffff0000u);
            a2 += a*__uint_as_float(pk.y<<16);
            a3 += a*__uint_as_float(pk.y&0xffff0000u);
        }
    } else {
        float lmax = -1e30f;
        for(int j=lane; j<d; j+=64){
            int sj = edge_src[rs+j];
            float t = ssrc[sj] + sd;
            lmax = fmaxf(lmax, fmaxf(t, 0.2f*t));
        }
        #pragma unroll
        for(int m=32;m>=1;m>>=1) lmax = fmaxf(lmax, __shfl_xor(lmax,m));
        float lsum = 0.f;
        for(int j=lane; j<d; j+=64){
            int sj = edge_src[rs+j];
            float t = ssrc[sj] + sd;
            lsum += __expf(fmaxf(t, 0.2f*t) - lmax);
        }
        #pragma unroll
        for(int m=32;m>=1;m>>=1) lsum += __shfl_xor(lsum,m);
        float inv = 1.0f/(lsum + 1e-16f);
        for(int cb=0; cb<d; cb+=64){
            int s2 = 0; float al = 0.f;
            int j = cb + lane;
            if(j < d){
                s2 = edge_src[rs+j];
                float t = ssrc[s2] + sd;
                al = __expf(fmaxf(t, 0.2f*t) - lmax) * inv;
            }
            int dd = min(d - cb, 64);
            for(int i0=0; i0<dd; i0+=4){
                int r  = i0 + grp;
                int rr = (r < dd) ? r : 0;
                float a = __shfl(al, rr);
                int  sj = __shfl(s2, rr);
                if(r >= dd) a = 0.f;
                uint2 pk = ((const uint2*)(hb + ((size_t)sj<<6)))[ch];
                a0 += a*__uint_as_float(pk.x<<16);
                a1 += a*__uint_as_float(pk.x&0xffff0000u);
                a2 += a*__uint_as_float(pk.y<<16);
                a3 += a*__uint_as_float(pk.y&0xffff0000u);
            }
        }
    }

    a0 += __shfl_xor(a0,32); a1 += __shfl_xor(a1,32);
    a2 += __shfl_xor(a2,32); a3 += __shfl_xor(a3,32);
    a0 += __shfl_xor(a0,16); a1 += __shfl_xor(a1,16);
    a2 += __shfl_xor(a2,16); a3 += __shfl_xor(a3,16);

    float4 bv = ((const float4*)bias)[ch];
    if(LAYER == 1){
        if(lane < 16){
            float v0 = tanhf(a0 + bv.x);
            float v1 = tanhf(a1 + bv.y);
            float v2 = tanhf(a2 + bv.z);
            float v3 = tanhf(a3 + bv.w);
            uint2 o;
            o.x = (unsigned)bfbits(v0) | ((unsigned)bfbits(v1) << 16);
            o.y = (unsigned)bfbits(v2) | ((unsigned)bfbits(v3) << 16);
            ((uint2*)(out1b + ((size_t)wid<<6)))[ch] = o;
        }
    } else {
        float4 wv = ((const float4*)Wl)[ch];
        float r = (a0+bv.x)*wv.x + (a1+bv.y)*wv.y + (a2+bv.z)*wv.z + (a3+bv.w)*wv.w;
        r += __shfl_xor(r,8); r += __shfl_xor(r,4);
        r += __shfl_xor(r,2); r += __shfl_xor(r,1);
        if(lane == 0) outF[wid] = r + bl[0];
    }
}

// ---------------- launch ----------------
extern "C" void kernel_launch(void* const* d_in, const int* in_sizes, int n_in,
                              void* d_out, int out_size, void* d_ws, size_t ws_size,
                              hipStream_t stream) {
    const float* x   = (const float*)d_in[0];
    const int*   ei  = (const int*)d_in[1];
    const float* W1  = (const float*)d_in[2];
    const float* as1 = (const float*)d_in[3];
    const float* ad1 = (const float*)d_in[4];
    const float* b1  = (const float*)d_in[5];
    const float* W2  = (const float*)d_in[6];
    const float* as2 = (const float*)d_in[7];
    const float* ad2 = (const float*)d_in[8];
    const float* b2  = (const float*)d_in[9];
    const float* Wl  = (const float*)d_in[10];
    const float* bl  = (const float*)d_in[11];
    float* out = (float*)d_out;

    const int* srcp = ei;
    const int* dstp = ei + NE;

    char* w = (char*)d_ws;
    int*   edge_src = (int*)w;  w += (size_t)ET*4;      //  6.8 MB
    bf16*  hb       = (bf16*)w; w += (size_t)NN*64*2;   // 12.8 MB
    bf16*  t1b      = (bf16*)w; w += (size_t)NN*64*2;   // 12.8 MB
    int*   rowst    = (int*)w;  w += (size_t)NN*4;
    int*   deg      = (int*)w;  w += (size_t)NN*4;
    float* ssrc     = (float*)w; w += (size_t)NN*4;
    float* sdst     = (float*)w; w += (size_t)NN*4;
    int*   bcnt     = (int*)w;  w += (size_t)NB*BST*4;
    int*   binbuf   = (int*)hb;     // aliases hb: dead before k_gemm<1> writes

    const int nbBin = (ET + 2047)/2048;     // 831
    const int nbA   = (NN + 3)/4;           // 25000

    hipMemsetAsync(bcnt, 0, (size_t)NB*BST*4, stream);
    k_bin  <<<nbBin, 256, 0, stream>>>(srcp, dstp, bcnt, binbuf);
    k_build<<<NB,    256, 0, stream>>>(bcnt, binbuf, edge_src, rowst, deg);

    // layer 1
    k_gemm<1><<<1024, 256, 0, stream>>>((const void*)x, W1, as1, ad1, hb, ssrc, sdst);
    k_agg<1><<<nbA, 256, 0, stream>>>(rowst, deg, edge_src, ssrc, sdst, hb,
                                      b1, (const float*)nullptr, (const float*)nullptr,
                                      t1b, (float*)nullptr);
    // layer 2 + final linear
    k_gemm<0><<<1024, 256, 0, stream>>>((const void*)t1b, W2, as2, ad2, hb, ssrc, sdst);
    k_agg<2><<<nbA, 256, 0, stream>>>(rowst, deg, edge_src, ssrc, sdst, hb,
                                      b2, Wl, bl,
                                      (bf16*)nullptr, out);
}

// Round 8
// 331.495 us; speedup vs baseline: 1.1971x; 1.1971x over previous
//
#include <hip/hip_runtime.h>
#include <hip/hip_bf16.h>

#define NN 100000
#define NE 1600000
#define ET (NE + NN)
#define NB 391          // buckets of 256 dst nodes
#define CAP 5120        // slots/bucket (mean 4352, +12 sigma)
#define BST 16          // bcnt pad: 64B per counter

typedef __hip_bfloat16 bf16;

__device__ __forceinline__ float bf2f(bf16 v){ return __bfloat162float(v); }
__device__ __forceinline__ unsigned short bfbits(float v){
    bf16 b = __float2bfloat16(v);
    return *(unsigned short*)&b;
}

// ---------------- CSR build: bin by dst>>8 ----------------
__global__ void __launch_bounds__(256) k_bin(const int* __restrict__ src,
        const int* __restrict__ dst, int* __restrict__ bcnt,
        int* __restrict__ binbuf){
    __shared__ int cnt[NB];
    __shared__ int cur[NB];
    int t = threadIdx.x;
    for(int i=t;i<NB;i+=256) cnt[i]=0;
    __syncthreads();
    int e0 = blockIdx.x*2048;
    #pragma unroll
    for(int k=0;k<8;k++){
        int e = e0 + k*256 + t;
        if(e < ET){ int d = (e < NE) ? dst[e] : (e - NE); atomicAdd(&cnt[d>>8], 1); }
    }
    __syncthreads();
    for(int i=t;i<NB;i+=256){ int c=cnt[i]; cur[i] = c ? atomicAdd(&bcnt[i*BST], c) : 0; }
    __syncthreads();
    #pragma unroll
    for(int k=0;k<8;k++){
        int e = e0 + k*256 + t;
        if(e < ET){
            int s, d;
            if(e < NE){ s = src[e]; d = dst[e]; } else { s = e - NE; d = s; }
            int b = d >> 8;
            int pos = atomicAdd(&cur[b], 1);
            if(pos < CAP) binbuf[b*CAP + pos] = (s << 8) | (d & 255);
        }
    }
}

// ---------------- CSR build: per-bucket dense build (base prefix fused) ----------------
__global__ void __launch_bounds__(256) k_build(const int* __restrict__ bcnt,
        const int* __restrict__ binbuf, int* __restrict__ edge_src,
        int* __restrict__ rowst, int* __restrict__ deg){
    __shared__ int lsrc[CAP];
    __shared__ int ldeg[256], lscan[256], lcur[256], red[256];
    int b = blockIdx.x, t = threadIdx.x;
    int cnt = min(bcnt[b*BST], CAP);
    int part = 0;
    for(int i=t;i<b;i+=256) part += min(bcnt[i*BST], CAP);
    red[t] = part; __syncthreads();
    for(int off=128; off>=1; off>>=1){ if(t<off) red[t]+=red[t+off]; __syncthreads(); }
    int base = red[0];
    __syncthreads();
    ldeg[t] = 0; __syncthreads();
    const int* bb = binbuf + b*CAP;
    for(int i=t;i<cnt;i+=256) atomicAdd(&ldeg[bb[i] & 255], 1);
    __syncthreads();
    int dv = ldeg[t]; lscan[t] = dv; __syncthreads();
    for(int off=1; off<256; off<<=1){
        int u = (t>=off) ? lscan[t-off] : 0;
        __syncthreads(); lscan[t] += u; __syncthreads();
    }
    int excl = lscan[t] - dv; lcur[t] = excl;
    int node = b*256 + t;
    if(node < NN){ rowst[node] = base + excl; deg[node] = dv; }
    __syncthreads();
    for(int i=t;i<cnt;i+=256){
        int ent = bb[i];
        int pos = atomicAdd(&lcur[ent & 255], 1);
        lsrc[pos] = ent >> 8;
    }
    __syncthreads();
    for(int i=t;i<cnt;i+=256) edge_src[base+i] = lsrc[i];
}

// ---------------- h = x@W, s_src, s_dst ----------------
// One block per 64-node tile. Stage x-tile in LDS with coalesced loads
// (kills the per-node global-latency chain), then wave w computes nodes
// w*16..w*16+15 from LDS broadcasts, 2 nodes in flight for FMA ILP.

template<int FPIN>
__global__ void __launch_bounds__(256) k_gemm(const void* __restrict__ xin,
        const float* __restrict__ W, const float* __restrict__ avs,
        const float* __restrict__ avd, bf16* __restrict__ hb,
        float* __restrict__ ssrc, float* __restrict__ sdst){
    __shared__ float xs[64*64];          // 16 KB fp32 tile (bf16 mode uses half)
    int t = threadIdx.x, wave = t>>6, lane = t&63;
    int tile = blockIdx.x*64;
    float Wreg[64];
    #pragma unroll
    for(int k=0;k<64;k++) Wreg[k] = W[k*64 + lane];
    float as = avs[lane], ad = avd[lane];

    if(FPIN){
        const float4* xg = (const float4*)((const float*)xin + (size_t)tile*64);
        float4* xl = (float4*)xs;
        #pragma unroll
        for(int i=0;i<4;i++){
            int idx = i*256 + t;                 // float4 index in tile (0..1023)
            int node = tile + (idx>>4);
            float4 v = make_float4(0.f,0.f,0.f,0.f);
            if(node < NN) v = xg[idx];
            xl[idx] = v;
        }
    } else {
        const uint4* xg = (const uint4*)((const bf16*)xin + (size_t)tile*64);
        uint4* xl = (uint4*)xs;
        #pragma unroll
        for(int i=0;i<2;i++){
            int idx = i*256 + t;                 // uint4 = 8 bf16 (0..511)
            int node = tile + (idx>>3);
            uint4 v = make_uint4(0,0,0,0);
            if(node < NN) v = xg[idx];
            xl[idx] = v;
        }
    }
    __syncthreads();

    #pragma unroll
    for(int i=0;i<16;i+=2){
        int l0 = wave*16 + i, l1 = l0 + 1;
        float p0=0.f,p1=0.f,p2=0.f,p3=0.f, q0=0.f,q1=0.f,q2=0.f,q3=0.f;
        if(FPIN){
            const float4* r0 = (const float4*)(xs + l0*64);
            const float4* r1 = (const float4*)(xs + l1*64);
            #pragma unroll
            for(int qq=0;qq<16;qq++){
                float4 u = r0[qq], v = r1[qq];   // LDS broadcast reads
                float w0=Wreg[4*qq+0], w1=Wreg[4*qq+1], w2=Wreg[4*qq+2], w3=Wreg[4*qq+3];
                p0 += u.x*w0; p1 += u.y*w1; p2 += u.z*w2; p3 += u.w*w3;
                q0 += v.x*w0; q1 += v.y*w1; q2 += v.z*w2; q3 += v.w*w3;
            }
        } else {
            const uint2* r0 = (const uint2*)((const bf16*)(const void*)xs + l0*64);
            const uint2* r1 = (const uint2*)((const bf16*)(const void*)xs + l1*64);
            #pragma unroll
            for(int qq=0;qq<16;qq++){
                uint2 u = r0[qq], v = r1[qq];    // 4 bf16 each
                float w0=Wreg[4*qq+0], w1=Wreg[4*qq+1], w2=Wreg[4*qq+2], w3=Wreg[4*qq+3];
                p0 += __uint_as_float(u.x<<16)*w0;         p1 += __uint_as_float(u.x&0xffff0000u)*w1;
                p2 += __uint_as_float(u.y<<16)*w2;         p3 += __uint_as_float(u.y&0xffff0000u)*w3;
                q0 += __uint_as_float(v.x<<16)*w0;         q1 += __uint_as_float(v.x&0xffff0000u)*w1;
                q2 += __uint_as_float(v.y<<16)*w2;         q3 += __uint_as_float(v.y&0xffff0000u)*w3;
            }
        }
        float A0 = (p0+p1) + (p2+p3);
        float A1 = (q0+q1) + (q2+q3);
        int n0 = tile + l0, n1 = tile + l1;
        if(n0 < NN) hb[(size_t)n0*64 + lane] = __float2bfloat16(A0);
        if(n1 < NN) hb[(size_t)n1*64 + lane] = __float2bfloat16(A1);
        float s0 = A0*as, d0 = A0*ad, s1 = A1*as, d1 = A1*ad;
        #pragma unroll
        for(int m=32;m>=1;m>>=1){
            s0 += __shfl_xor(s0,m); d0 += __shfl_xor(d0,m);
            s1 += __shfl_xor(s1,m); d1 += __shfl_xor(d1,m);
        }
        if(lane==0){
            if(n0 < NN){ ssrc[n0] = s0; sdst[n0] = d0; }
            if(n1 < NN){ ssrc[n1] = s1; sdst[n1] = d1; }
        }
    }
}

// ---------------- attention + aggregation ----------------
// wave per dst node; gather vectorized: uint2/lane = 4 rows (512B) per iteration.

template<int LAYER>
__global__ void __launch_bounds__(256) k_agg(
        const int* __restrict__ rowst, const int* __restrict__ deg,
        const int* __restrict__ edge_src,
        const float* __restrict__ ssrc, const float* __restrict__ sdst,
        const bf16* __restrict__ hb,
        const float* __restrict__ bias, const float* __restrict__ Wl,
        const float* __restrict__ bl,
        bf16* __restrict__ out1b, float* __restrict__ outF){
    int wid  = (blockIdx.x*256 + threadIdx.x) >> 6;
    int lane = threadIdx.x & 63;
    if(wid >= NN) return;
    int rs = rowst[wid];
    int d  = deg[wid];
    float sd = sdst[wid];
    int grp = lane >> 4;
    int ch  = lane & 15;                 // channel chunk: bf16 channels ch*4 .. ch*4+3
    float a0=0.f, a1=0.f, a2=0.f, a3=0.f;

    if(d <= 64){
        int s = 0; float e = -1e30f;
        if(lane < d){
            s = edge_src[rs + lane];
            float t = ssrc[s] + sd;
            e = fmaxf(t, 0.2f*t);        // leaky_relu
        }
        float mx = e;
        #pragma unroll
        for(int m=32;m>=1;m>>=1) mx = fmaxf(mx, __shfl_xor(mx,m));
        float pr = (lane < d) ? __expf(e - mx) : 0.f;
        float sm = pr;
        #pragma unroll
        for(int m=32;m>=1;m>>=1) sm += __shfl_xor(sm,m);
        float alpha = pr * (1.0f/(sm + 1e-16f));
        for(int i0=0; i0<d; i0+=4){
            int r  = i0 + grp;
            int rr = (r < d) ? r : 0;
            float a = __shfl(alpha, rr);
            int  sj = __shfl(s, rr);
            if(r >= d) a = 0.f;
            uint2 pk = ((const uint2*)(hb + ((size_t)sj<<6)))[ch];
            a0 += a*__uint_as_float(pk.x<<16);
            a1 += a*__uint_as_float(pk.x&0xffff0000u);
            a2 += a*__uint_as_float(pk.y<<16);
            a3 += a*__uint_as_float(pk.y&0xffff0000u);
        }
    } else {
        float lmax = -1e30f;
        for(int j=lane; j<d; j+=64){
            int sj = edge_src[rs+j];
            float t = ssrc[sj] + sd;
            lmax = fmaxf(lmax, fmaxf(t, 0.2f*t));
        }
        #pragma unroll
        for(int m=32;m>=1;m>>=1) lmax = fmaxf(lmax, __shfl_xor(lmax,m));
        float lsum = 0.f;
        for(int j=lane; j<d; j+=64){
            int sj = edge_src[rs+j];
            float t = ssrc[sj] + sd;
            lsum += __expf(fmaxf(t, 0.2f*t) - lmax);
        }
        #pragma unroll
        for(int m=32;m>=1;m>>=1) lsum += __shfl_xor(lsum,m);
        float inv = 1.0f/(lsum + 1e-16f);
        for(int cb=0; cb<d; cb+=64){
            int s2 = 0; float al = 0.f;
            int j = cb + lane;
            if(j < d){
                s2 = edge_src[rs+j];
                float t = ssrc[s2] + sd;
                al = __expf(fmaxf(t, 0.2f*t) - lmax) * inv;
            }
            int dd = min(d - cb, 64);
            for(int i0=0; i0<dd; i0+=4){
                int r  = i0 + grp;
                int rr = (r < dd) ? r : 0;
                float a = __shfl(al, rr);
                int  sj = __shfl(s2, rr);
                if(r >= dd) a = 0.f;
                uint2 pk = ((const uint2*)(hb + ((size_t)sj<<6)))[ch];
                a0 += a*__uint_as_float(pk.x<<16);
                a1 += a*__uint_as_float(pk.x&0xffff0000u);
                a2 += a*__uint_as_float(pk.y<<16);
                a3 += a*__uint_as_float(pk.y&0xffff0000u);
            }
        }
    }

    a0 += __shfl_xor(a0,32); a1 += __shfl_xor(a1,32);
    a2 += __shfl_xor(a2,32); a3 += __shfl_xor(a3,32);
    a0 += __shfl_xor(a0,16); a1 += __shfl_xor(a1,16);
    a2 += __shfl_xor(a2,16); a3 += __shfl_xor(a3,16);

    float4 bv = ((const float4*)bias)[ch];
    if(LAYER == 1){
        if(lane < 16){
            float v0 = tanhf(a0 + bv.x);
            float v1 = tanhf(a1 + bv.y);
            float v2 = tanhf(a2 + bv.z);
            float v3 = tanhf(a3 + bv.w);
            uint2 o;
            o.x = (unsigned)bfbits(v0) | ((unsigned)bfbits(v1) << 16);
            o.y = (unsigned)bfbits(v2) | ((unsigned)bfbits(v3) << 16);
            ((uint2*)(out1b + ((size_t)wid<<6)))[ch] = o;
        }
    } else {
        float4 wv = ((const float4*)Wl)[ch];
        float r = (a0+bv.x)*wv.x + (a1+bv.y)*wv.y + (a2+bv.z)*wv.z + (a3+bv.w)*wv.w;
        r += __shfl_xor(r,8); r += __shfl_xor(r,4);
        r += __shfl_xor(r,2); r += __shfl_xor(r,1);
        if(lane == 0) outF[wid] = r + bl[0];
    }
}

// ---------------- launch ----------------
extern "C" void kernel_launch(void* const* d_in, const int* in_sizes, int n_in,
                              void* d_out, int out_size, void* d_ws, size_t ws_size,
                              hipStream_t stream) {
    const float* x   = (const float*)d_in[0];
    const int*   ei  = (const int*)d_in[1];
    const float* W1  = (const float*)d_in[2];
    const float* as1 = (const float*)d_in[3];
    const float* ad1 = (const float*)d_in[4];
    const float* b1  = (const float*)d_in[5];
    const float* W2  = (const float*)d_in[6];
    const float* as2 = (const float*)d_in[7];
    const float* ad2 = (const float*)d_in[8];
    const float* b2  = (const float*)d_in[9];
    const float* Wl  = (const float*)d_in[10];
    const float* bl  = (const float*)d_in[11];
    float* out = (float*)d_out;

    const int* srcp = ei;
    const int* dstp = ei + NE;

    char* w = (char*)d_ws;
    int*   edge_src = (int*)w;  w += (size_t)ET*4;      //  6.8 MB
    bf16*  hb       = (bf16*)w; w += (size_t)NN*64*2;   // 12.8 MB
    bf16*  t1b      = (bf16*)w; w += (size_t)NN*64*2;   // 12.8 MB
    int*   rowst    = (int*)w;  w += (size_t)NN*4;
    int*   deg      = (int*)w;  w += (size_t)NN*4;
    float* ssrc     = (float*)w; w += (size_t)NN*4;
    float* sdst     = (float*)w; w += (size_t)NN*4;
    int*   bcnt     = (int*)w;  w += (size_t)NB*BST*4;
    int*   binbuf   = (int*)hb;     // aliases hb: dead before k_gemm<1> writes

    const int nbBin = (ET + 2047)/2048;     // 831
    const int nbG   = (NN + 63)/64;         // 1563
    const int nbA   = (NN + 3)/4;           // 25000

    hipMemsetAsync(bcnt, 0, (size_t)NB*BST*4, stream);
    k_bin  <<<nbBin, 256, 0, stream>>>(srcp, dstp, bcnt, binbuf);
    k_build<<<NB,    256, 0, stream>>>(bcnt, binbuf, edge_src, rowst, deg);

    // layer 1
    k_gemm<1><<<nbG, 256, 0, stream>>>((const void*)x, W1, as1, ad1, hb, ssrc, sdst);
    k_agg<1><<<nbA, 256, 0, stream>>>(rowst, deg, edge_src, ssrc, sdst, hb,
                                      b1, (const float*)nullptr, (const float*)nullptr,
                                      t1b, (float*)nullptr);
    // layer 2 + final linear
    k_gemm<0><<<nbG, 256, 0, stream>>>((const void*)t1b, W2, as2, ad2, hb, ssrc, sdst);
    k_agg<2><<<nbA, 256, 0, stream>>>(rowst, deg, edge_src, ssrc, sdst, hb,
                                      b2, Wl, bl,
                                      (bf16*)nullptr, out);
}

// Round 9
// 315.256 us; speedup vs baseline: 1.2588x; 1.0515x over previous
//
#include <hip/hip_runtime.h>
#include <hip/hip_bf16.h>

#define NN 100000
#define NE 1600000
#define ET (NE + NN)
#define NB 391          // buckets of 256 dst nodes
#define CAP 5120        // slots/bucket (mean 4352, +12 sigma)
#define BST 16          // bcnt pad: 64B per counter

typedef __hip_bfloat16 bf16;

__device__ __forceinline__ float bf2f(bf16 v){ return __bfloat162float(v); }
__device__ __forceinline__ unsigned short bfbits(float v){
    bf16 b = __float2bfloat16(v);
    return *(unsigned short*)&b;
}
__device__ __forceinline__ float fast_tanh(float x){
    // 1 - 2/(e^{2x}+1); exact at +-inf, ~1e-7 rel err, ~6 instrs
    float e = __expf(2.f*x);
    return 1.f - __fdividef(2.f, e + 1.f);
}

// ---------------- CSR build: bin by dst>>8 ----------------
__global__ void __launch_bounds__(256) k_bin(const int* __restrict__ src,
        const int* __restrict__ dst, int* __restrict__ bcnt,
        int* __restrict__ binbuf){
    __shared__ int cnt[NB];
    __shared__ int cur[NB];
    int t = threadIdx.x;
    for(int i=t;i<NB;i+=256) cnt[i]=0;
    __syncthreads();
    int e0 = blockIdx.x*2048;
    #pragma unroll
    for(int k=0;k<8;k++){
        int e = e0 + k*256 + t;
        if(e < ET){ int d = (e < NE) ? dst[e] : (e - NE); atomicAdd(&cnt[d>>8], 1); }
    }
    __syncthreads();
    for(int i=t;i<NB;i+=256){ int c=cnt[i]; cur[i] = c ? atomicAdd(&bcnt[i*BST], c) : 0; }
    __syncthreads();
    #pragma unroll
    for(int k=0;k<8;k++){
        int e = e0 + k*256 + t;
        if(e < ET){
            int s, d;
            if(e < NE){ s = src[e]; d = dst[e]; } else { s = e - NE; d = s; }
            int b = d >> 8;
            int pos = atomicAdd(&cur[b], 1);
            if(pos < CAP) binbuf[b*CAP + pos] = (s << 8) | (d & 255);
        }
    }
}

// ---------------- CSR build: per-bucket dense build (base prefix fused) ----------------
__global__ void __launch_bounds__(256) k_build(const int* __restrict__ bcnt,
        const int* __restrict__ binbuf, int* __restrict__ edge_src,
        int* __restrict__ rowst, int* __restrict__ deg){
    __shared__ int lsrc[CAP];
    __shared__ int ldeg[256], lscan[256], lcur[256], red[256];
    int b = blockIdx.x, t = threadIdx.x;
    int cnt = min(bcnt[b*BST], CAP);
    int part = 0;
    for(int i=t;i<b;i+=256) part += min(bcnt[i*BST], CAP);
    red[t] = part; __syncthreads();
    for(int off=128; off>=1; off>>=1){ if(t<off) red[t]+=red[t+off]; __syncthreads(); }
    int base = red[0];
    __syncthreads();
    ldeg[t] = 0; __syncthreads();
    const int* bb = binbuf + b*CAP;
    for(int i=t;i<cnt;i+=256) atomicAdd(&ldeg[bb[i] & 255], 1);
    __syncthreads();
    int dv = ldeg[t]; lscan[t] = dv; __syncthreads();
    for(int off=1; off<256; off<<=1){
        int u = (t>=off) ? lscan[t-off] : 0;
        __syncthreads(); lscan[t] += u; __syncthreads();
    }
    int excl = lscan[t] - dv; lcur[t] = excl;
    int node = b*256 + t;
    if(node < NN){ rowst[node] = base + excl; deg[node] = dv; }
    __syncthreads();
    for(int i=t;i<cnt;i+=256){
        int ent = bb[i];
        int pos = atomicAdd(&lcur[ent & 255], 1);
        lsrc[pos] = ent >> 8;
    }
    __syncthreads();
    for(int i=t;i<cnt;i+=256) edge_src[base+i] = lsrc[i];
}

// ---------------- h = x@W, s_src, s_dst (LDS-staged tile) ----------------
template<int FPIN>
__global__ void __launch_bounds__(256) k_gemm(const void* __restrict__ xin,
        const float* __restrict__ W, const float* __restrict__ avs,
        const float* __restrict__ avd, bf16* __restrict__ hb,
        float* __restrict__ ssrc, float* __restrict__ sdst){
    __shared__ float xs[64*64];          // 16 KB fp32 tile (bf16 mode uses half)
    int t = threadIdx.x, wave = t>>6, lane = t&63;
    int tile = blockIdx.x*64;
    float Wreg[64];
    #pragma unroll
    for(int k=0;k<64;k++) Wreg[k] = W[k*64 + lane];
    float as = avs[lane], ad = avd[lane];

    if(FPIN){
        const float4* xg = (const float4*)((const float*)xin + (size_t)tile*64);
        float4* xl = (float4*)xs;
        #pragma unroll
        for(int i=0;i<4;i++){
            int idx = i*256 + t;
            int node = tile + (idx>>4);
            float4 v = make_float4(0.f,0.f,0.f,0.f);
            if(node < NN) v = xg[idx];
            xl[idx] = v;
        }
    } else {
        const uint4* xg = (const uint4*)((const bf16*)xin + (size_t)tile*64);
        uint4* xl = (uint4*)xs;
        #pragma unroll
        for(int i=0;i<2;i++){
            int idx = i*256 + t;
            int node = tile + (idx>>3);
            uint4 v = make_uint4(0,0,0,0);
            if(node < NN) v = xg[idx];
            xl[idx] = v;
        }
    }
    __syncthreads();

    #pragma unroll
    for(int i=0;i<16;i+=2){
        int l0 = wave*16 + i, l1 = l0 + 1;
        float p0=0.f,p1=0.f,p2=0.f,p3=0.f, q0=0.f,q1=0.f,q2=0.f,q3=0.f;
        if(FPIN){
            const float4* r0 = (const float4*)(xs + l0*64);
            const float4* r1 = (const float4*)(xs + l1*64);
            #pragma unroll
            for(int qq=0;qq<16;qq++){
                float4 u = r0[qq], v = r1[qq];
                float w0=Wreg[4*qq+0], w1=Wreg[4*qq+1], w2=Wreg[4*qq+2], w3=Wreg[4*qq+3];
                p0 += u.x*w0; p1 += u.y*w1; p2 += u.z*w2; p3 += u.w*w3;
                q0 += v.x*w0; q1 += v.y*w1; q2 += v.z*w2; q3 += v.w*w3;
            }
        } else {
            const uint2* r0 = (const uint2*)((const bf16*)(const void*)xs + l0*64);
            const uint2* r1 = (const uint2*)((const bf16*)(const void*)xs + l1*64);
            #pragma unroll
            for(int qq=0;qq<16;qq++){
                uint2 u = r0[qq], v = r1[qq];
                float w0=Wreg[4*qq+0], w1=Wreg[4*qq+1], w2=Wreg[4*qq+2], w3=Wreg[4*qq+3];
                p0 += __uint_as_float(u.x<<16)*w0;         p1 += __uint_as_float(u.x&0xffff0000u)*w1;
                p2 += __uint_as_float(u.y<<16)*w2;         p3 += __uint_as_float(u.y&0xffff0000u)*w3;
                q0 += __uint_as_float(v.x<<16)*w0;         q1 += __uint_as_float(v.x&0xffff0000u)*w1;
                q2 += __uint_as_float(v.y<<16)*w2;         q3 += __uint_as_float(v.y&0xffff0000u)*w3;
            }
        }
        float A0 = (p0+p1) + (p2+p3);
        float A1 = (q0+q1) + (q2+q3);
        int n0 = tile + l0, n1 = tile + l1;
        if(n0 < NN) hb[(size_t)n0*64 + lane] = __float2bfloat16(A0);
        if(n1 < NN) hb[(size_t)n1*64 + lane] = __float2bfloat16(A1);
        float s0 = A0*as, d0 = A0*ad, s1 = A1*as, d1 = A1*ad;
        #pragma unroll
        for(int m=32;m>=1;m>>=1){
            s0 += __shfl_xor(s0,m); d0 += __shfl_xor(d0,m);
            s1 += __shfl_xor(s1,m); d1 += __shfl_xor(d1,m);
        }
        if(lane==0){
            if(n0 < NN){ ssrc[n0] = s0; sdst[n0] = d0; }
            if(n1 < NN){ ssrc[n1] = s1; sdst[n1] = d1; }
        }
    }
}

// ---------------- attention + aggregation ----------------
// wave per dst node. Fast path: no max-pass (clamped exp), LDS (alpha,src)
// pair table instead of per-iter shuffles, 8 edges/iter with 2 loads in flight.

template<int LAYER>
__global__ void __launch_bounds__(256) k_agg(
        const int* __restrict__ rowst, const int* __restrict__ deg,
        const int* __restrict__ edge_src,
        const float* __restrict__ ssrc, const float* __restrict__ sdst,
        const bf16* __restrict__ hb,
        const float* __restrict__ bias, const float* __restrict__ Wl,
        const float* __restrict__ bl,
        bf16* __restrict__ out1b, float* __restrict__ outF){
    __shared__ int2 pairs[256];          // 4 waves x 64 (alpha-bits, src)
    int tid = threadIdx.x;
    int wid  = (blockIdx.x*256 + tid) >> 6;
    int lane = tid & 63;
    if(wid >= NN) return;
    int2* lp = pairs + (tid & 192);      // wave-private 64-entry table
    int rs = rowst[wid];
    int d  = deg[wid];
    float sd = sdst[wid];
    int grp = lane >> 4;
    int ch  = lane & 15;                 // channel chunk: bf16 channels ch*4 .. ch*4+3
    float a0=0.f, a1=0.f, a2=0.f, a3=0.f;

    if(d <= 64){
        int s = 0; float p = 0.f;
        if(lane < d){
            s = edge_src[rs + lane];
            float t = ssrc[s] + sd;
            t = fmaxf(t, 0.2f*t);        // leaky_relu
            p = __expf(fminf(t, 80.f));  // no max-shift: logits O(10), safe
        }
        float sm = p;
        #pragma unroll
        for(int m=32;m>=1;m>>=1) sm += __shfl_xor(sm,m);
        float alpha = p * (1.0f/(sm + 1e-16f));
        lp[lane] = make_int2(__float_as_int(alpha), s);   // lanes>=d: alpha=0, s=0
        for(int i0=0; i0<d; i0+=8){
            int2 e0 = lp[i0 + grp];          // ds_read_b64, 16-lane broadcast
            int2 e1 = lp[i0 + 4 + grp];
            float f0 = __int_as_float(e0.x);
            float f1 = __int_as_float(e1.x);
            uint2 k0 = ((const uint2*)(hb + ((size_t)e0.y<<6)))[ch];
            uint2 k1 = ((const uint2*)(hb + ((size_t)e1.y<<6)))[ch];
            a0 += f0*__uint_as_float(k0.x<<16);
            a1 += f0*__uint_as_float(k0.x&0xffff0000u);
            a2 += f0*__uint_as_float(k0.y<<16);
            a3 += f0*__uint_as_float(k0.y&0xffff0000u);
            a0 += f1*__uint_as_float(k1.x<<16);
            a1 += f1*__uint_as_float(k1.x&0xffff0000u);
            a2 += f1*__uint_as_float(k1.y<<16);
            a3 += f1*__uint_as_float(k1.y&0xffff0000u);
        }
    } else {
        // generic path (d>64): essentially never at Poisson(17); keep max for safety
        float lmax = -1e30f;
        for(int j=lane; j<d; j+=64){
            int sj = edge_src[rs+j];
            float t = ssrc[sj] + sd;
            lmax = fmaxf(lmax, fmaxf(t, 0.2f*t));
        }
        #pragma unroll
        for(int m=32;m>=1;m>>=1) lmax = fmaxf(lmax, __shfl_xor(lmax,m));
        float lsum = 0.f;
        for(int j=lane; j<d; j+=64){
            int sj = edge_src[rs+j];
            float t = ssrc[sj] + sd;
            lsum += __expf(fmaxf(t, 0.2f*t) - lmax);
        }
        #pragma unroll
        for(int m=32;m>=1;m>>=1) lsum += __shfl_xor(lsum,m);
        float inv = 1.0f/(lsum + 1e-16f);
        for(int cb=0; cb<d; cb+=64){
            int s2 = 0; float al = 0.f;
            int j = cb + lane;
            if(j < d){
                s2 = edge_src[rs+j];
                float t = ssrc[s2] + sd;
                al = __expf(fmaxf(t, 0.2f*t) - lmax) * inv;
            }
            lp[lane] = make_int2(__float_as_int(al), s2);
            int dd = min(d - cb, 64);
            for(int i0=0; i0<dd; i0+=8){
                int2 e0 = lp[i0 + grp];
                int2 e1 = lp[i0 + 4 + grp];
                float f0 = __int_as_float(e0.x);
                float f1 = __int_as_float(e1.x);
                uint2 k0 = ((const uint2*)(hb + ((size_t)e0.y<<6)))[ch];
                uint2 k1 = ((const uint2*)(hb + ((size_t)e1.y<<6)))[ch];
                a0 += f0*__uint_as_float(k0.x<<16);
                a1 += f0*__uint_as_float(k0.x&0xffff0000u);
                a2 += f0*__uint_as_float(k0.y<<16);
                a3 += f0*__uint_as_float(k0.y&0xffff0000u);
                a0 += f1*__uint_as_float(k1.x<<16);
                a1 += f1*__uint_as_float(k1.x&0xffff0000u);
                a2 += f1*__uint_as_float(k1.y<<16);
                a3 += f1*__uint_as_float(k1.y&0xffff0000u);
            }
        }
    }

    a0 += __shfl_xor(a0,32); a1 += __shfl_xor(a1,32);
    a2 += __shfl_xor(a2,32); a3 += __shfl_xor(a3,32);
    a0 += __shfl_xor(a0,16); a1 += __shfl_xor(a1,16);
    a2 += __shfl_xor(a2,16); a3 += __shfl_xor(a3,16);

    float4 bv = ((const float4*)bias)[ch];
    if(LAYER == 1){
        if(lane < 16){
            float v0 = fast_tanh(a0 + bv.x);
            float v1 = fast_tanh(a1 + bv.y);
            float v2 = fast_tanh(a2 + bv.z);
            float v3 = fast_tanh(a3 + bv.w);
            uint2 o;
            o.x = (unsigned)bfbits(v0) | ((unsigned)bfbits(v1) << 16);
            o.y = (unsigned)bfbits(v2) | ((unsigned)bfbits(v3) << 16);
            ((uint2*)(out1b + ((size_t)wid<<6)))[ch] = o;
        }
    } else {
        float4 wv = ((const float4*)Wl)[ch];
        float r = (a0+bv.x)*wv.x + (a1+bv.y)*wv.y + (a2+bv.z)*wv.z + (a3+bv.w)*wv.w;
        r += __shfl_xor(r,8); r += __shfl_xor(r,4);
        r += __shfl_xor(r,2); r += __shfl_xor(r,1);
        if(lane == 0) outF[wid] = r + bl[0];
    }
}

// ---------------- launch ----------------
extern "C" void kernel_launch(void* const* d_in, const int* in_sizes, int n_in,
                              void* d_out, int out_size, void* d_ws, size_t ws_size,
                              hipStream_t stream) {
    const float* x   = (const float*)d_in[0];
    const int*   ei  = (const int*)d_in[1];
    const float* W1  = (const float*)d_in[2];
    const float* as1 = (const float*)d_in[3];
    const float* ad1 = (const float*)d_in[4];
    const float* b1  = (const float*)d_in[5];
    const float* W2  = (const float*)d_in[6];
    const float* as2 = (const float*)d_in[7];
    const float* ad2 = (const float*)d_in[8];
    const float* b2  = (const float*)d_in[9];
    const float* Wl  = (const float*)d_in[10];
    const float* bl  = (const float*)d_in[11];
    float* out = (float*)d_out;

    const int* srcp = ei;
    const int* dstp = ei + NE;

    char* w = (char*)d_ws;
    int*   edge_src = (int*)w;  w += (size_t)ET*4;      //  6.8 MB
    bf16*  hb       = (bf16*)w; w += (size_t)NN*64*2;   // 12.8 MB
    bf16*  t1b      = (bf16*)w; w += (size_t)NN*64*2;   // 12.8 MB
    int*   rowst    = (int*)w;  w += (size_t)NN*4;
    int*   deg      = (int*)w;  w += (size_t)NN*4;
    float* ssrc     = (float*)w; w += (size_t)NN*4;
    float* sdst     = (float*)w; w += (size_t)NN*4;
    int*   bcnt     = (int*)w;  w += (size_t)NB*BST*4;
    int*   binbuf   = (int*)hb;     // aliases hb: dead before k_gemm<1> writes

    const int nbBin = (ET + 2047)/2048;     // 831
    const int nbG   = (NN + 63)/64;         // 1563
    const int nbA   = (NN + 3)/4;           // 25000

    hipMemsetAsync(bcnt, 0, (size_t)NB*BST*4, stream);
    k_bin  <<<nbBin, 256, 0, stream>>>(srcp, dstp, bcnt, binbuf);
    k_build<<<NB,    256, 0, stream>>>(bcnt, binbuf, edge_src, rowst, deg);

    // layer 1
    k_gemm<1><<<nbG, 256, 0, stream>>>((const void*)x, W1, as1, ad1, hb, ssrc, sdst);
    k_agg<1><<<nbA, 256, 0, stream>>>(rowst, deg, edge_src, ssrc, sdst, hb,
                                      b1, (const float*)nullptr, (const float*)nullptr,
                                      t1b, (float*)nullptr);
    // layer 2 + final linear
    k_gemm<0><<<nbG, 256, 0, stream>>>((const void*)t1b, W2, as2, ad2, hb, ssrc, sdst);
    k_agg<2><<<nbA, 256, 0, stream>>>(rowst, deg, edge_src, ssrc, sdst, hb,
                                      b2, Wl, bl,
                                      (bf16*)nullptr, out);
}

// Round 10
// 275.786 us; speedup vs baseline: 1.4389x; 1.1431x over previous
//
#include <hip/hip_runtime.h>
#include <hip/hip_bf16.h>

#define NN 100000
#define NE 1600000
#define ET (NE + NN)
#define NB 391          // buckets of 256 dst nodes
#define CAP 5120        // slots/bucket (mean 4352, +12 sigma)
#define BST 16          // bcnt pad: 64B per counter

typedef __hip_bfloat16 bf16;
typedef __attribute__((ext_vector_type(8))) short short8;
typedef __attribute__((ext_vector_type(4))) float f32x4;

__device__ __forceinline__ float bf2f(bf16 v){ return __bfloat162float(v); }
__device__ __forceinline__ unsigned short bfbits(float v){
    bf16 b = __float2bfloat16(v);
    return *(unsigned short*)&b;
}
__device__ __forceinline__ float fast_tanh(float x){
    float e = __expf(2.f*x);
    return 1.f - __fdividef(2.f, e + 1.f);
}

// ---------------- CSR build: bin by dst>>8 ----------------
__global__ void __launch_bounds__(256) k_bin(const int* __restrict__ src,
        const int* __restrict__ dst, int* __restrict__ bcnt,
        int* __restrict__ binbuf){
    __shared__ int cnt[NB];
    __shared__ int cur[NB];
    int t = threadIdx.x;
    for(int i=t;i<NB;i+=256) cnt[i]=0;
    __syncthreads();
    int e0 = blockIdx.x*2048;
    #pragma unroll
    for(int k=0;k<8;k++){
        int e = e0 + k*256 + t;
        if(e < ET){ int d = (e < NE) ? dst[e] : (e - NE); atomicAdd(&cnt[d>>8], 1); }
    }
    __syncthreads();
    for(int i=t;i<NB;i+=256){ int c=cnt[i]; cur[i] = c ? atomicAdd(&bcnt[i*BST], c) : 0; }
    __syncthreads();
    #pragma unroll
    for(int k=0;k<8;k++){
        int e = e0 + k*256 + t;
        if(e < ET){
            int s, d;
            if(e < NE){ s = src[e]; d = dst[e]; } else { s = e - NE; d = s; }
            int b = d >> 8;
            int pos = atomicAdd(&cur[b], 1);
            if(pos < CAP) binbuf[b*CAP + pos] = (s << 8) | (d & 255);
        }
    }
}

// ---------------- CSR build: per-bucket dense build (base prefix fused) ----------------
__global__ void __launch_bounds__(256) k_build(const int* __restrict__ bcnt,
        const int* __restrict__ binbuf, int* __restrict__ edge_src,
        int* __restrict__ rowst, int* __restrict__ deg){
    __shared__ int lsrc[CAP];
    __shared__ int ldeg[256], lscan[256], lcur[256], red[256];
    int b = blockIdx.x, t = threadIdx.x;
    int cnt = min(bcnt[b*BST], CAP);
    int part = 0;
    for(int i=t;i<b;i+=256) part += min(bcnt[i*BST], CAP);
    red[t] = part; __syncthreads();
    for(int off=128; off>=1; off>>=1){ if(t<off) red[t]+=red[t+off]; __syncthreads(); }
    int base = red[0];
    __syncthreads();
    ldeg[t] = 0; __syncthreads();
    const int* bb = binbuf + b*CAP;
    for(int i=t;i<cnt;i+=256) atomicAdd(&ldeg[bb[i] & 255], 1);
    __syncthreads();
    int dv = ldeg[t]; lscan[t] = dv; __syncthreads();
    for(int off=1; off<256; off<<=1){
        int u = (t>=off) ? lscan[t-off] : 0;
        __syncthreads(); lscan[t] += u; __syncthreads();
    }
    int excl = lscan[t] - dv; lcur[t] = excl;
    int node = b*256 + t;
    if(node < NN){ rowst[node] = base + excl; deg[node] = dv; }
    __syncthreads();
    for(int i=t;i<cnt;i+=256){
        int ent = bb[i];
        int pos = atomicAdd(&lcur[ent & 255], 1);
        lsrc[pos] = ent >> 8;
    }
    __syncthreads();
    for(int i=t;i<cnt;i+=256) edge_src[base+i] = lsrc[i];
}

// ---------------- h = x@W via MFMA, s_src, s_dst ----------------
// One 16-node tile per wave-iteration. A-frag loaded straight from global
// (lane m=lane&15 reads x[n0+m][kh*32+q*8..+7]); W held as 8 short8 B-frags.
// D layout: col=lane&15, row=(lane>>4)*4+reg (m89-verified).

template<int FPIN>
__global__ void __launch_bounds__(256) k_gemm(const void* __restrict__ xin,
        const float* __restrict__ W, const float* __restrict__ avs,
        const float* __restrict__ avd, bf16* __restrict__ hb,
        float* __restrict__ ssrc, float* __restrict__ sdst){
    int tid = threadIdx.x, lane = tid & 63;
    int col = lane & 15, q = lane >> 4;

    // B fragments: B[k][n], n = col (+nb*16), k = kh*32 + q*8 + j
    short8 Bf[2][4];
    #pragma unroll
    for(int kh=0;kh<2;kh++){
        #pragma unroll
        for(int nb=0;nb<4;nb++){
            short8 b;
            #pragma unroll
            for(int j=0;j<8;j++){
                float w = W[(kh*32 + q*8 + j)*64 + nb*16 + col];
                b[j] = (short)bfbits(w);
            }
            Bf[kh][nb] = b;
        }
    }
    float as[4], ad[4];
    #pragma unroll
    for(int nb=0;nb<4;nb++){ as[nb] = avs[nb*16+col]; ad[nb] = avd[nb*16+col]; }

    int gw = (blockIdx.x*256 + tid) >> 6;
    int nwaves = gridDim.x*4;
    for(int tile = gw; tile < NN/16; tile += nwaves){
        int n0 = tile*16;
        f32x4 acc[4];
        #pragma unroll
        for(int nb=0;nb<4;nb++) acc[nb] = (f32x4){0.f,0.f,0.f,0.f};

        #pragma unroll
        for(int kh=0;kh<2;kh++){
            short8 a;
            if(FPIN){
                const float4* xr = (const float4*)((const float*)xin
                                    + (size_t)(n0+col)*64 + kh*32 + q*8);
                float4 u = xr[0], v = xr[1];
                a[0]=(short)bfbits(u.x); a[1]=(short)bfbits(u.y);
                a[2]=(short)bfbits(u.z); a[3]=(short)bfbits(u.w);
                a[4]=(short)bfbits(v.x); a[5]=(short)bfbits(v.y);
                a[6]=(short)bfbits(v.z); a[7]=(short)bfbits(v.w);
            } else {
                a = *(const short8*)((const bf16*)xin
                                    + (size_t)(n0+col)*64 + kh*32 + q*8);
            }
            #pragma unroll
            for(int nb=0;nb<4;nb++)
                acc[nb] = __builtin_amdgcn_mfma_f32_16x16x32_bf16(a, Bf[kh][nb], acc[nb], 0,0,0);
        }

        // store h (D: row = q*4+r, col = nb*16+col)
        #pragma unroll
        for(int nb=0;nb<4;nb++){
            #pragma unroll
            for(int r=0;r<4;r++)
                hb[(size_t)(n0 + q*4 + r)*64 + nb*16 + col] = __float2bfloat16(acc[nb][r]);
        }
        // ssrc/sdst: dot rows with a_src/a_dst, reduce over the 16 cols
        #pragma unroll
        for(int r=0;r<4;r++){
            float ps = acc[0][r]*as[0] + acc[1][r]*as[1] + acc[2][r]*as[2] + acc[3][r]*as[3];
            float pd = acc[0][r]*ad[0] + acc[1][r]*ad[1] + acc[2][r]*ad[2] + acc[3][r]*ad[3];
            #pragma unroll
            for(int m=8;m>=1;m>>=1){ ps += __shfl_xor(ps,m); pd += __shfl_xor(pd,m); }
            if(col == 0){ ssrc[n0 + q*4 + r] = ps; sdst[n0 + q*4 + r] = pd; }
        }
    }
}

// ---------------- attention + aggregation ----------------
// wave per dst node; no max-pass (clamped exp), LDS (alpha,src) pair table,
// 8 edges/iter with 2 gather loads in flight.

template<int LAYER>
__global__ void __launch_bounds__(256) k_agg(
        const int* __restrict__ rowst, const int* __restrict__ deg,
        const int* __restrict__ edge_src,
        const float* __restrict__ ssrc, const float* __restrict__ sdst,
        const bf16* __restrict__ hb,
        const float* __restrict__ bias, const float* __restrict__ Wl,
        const float* __restrict__ bl,
        bf16* __restrict__ out1b, float* __restrict__ outF){
    __shared__ int2 pairs[256];
    int tid = threadIdx.x;
    int wid  = (blockIdx.x*256 + tid) >> 6;
    int lane = tid & 63;
    if(wid >= NN) return;
    int2* lp = pairs + (tid & 192);
    int rs = rowst[wid];
    int d  = deg[wid];
    float sd = sdst[wid];
    int grp = lane >> 4;
    int ch  = lane & 15;
    float a0=0.f, a1=0.f, a2=0.f, a3=0.f;

    if(d <= 64){
        int s = 0; float p = 0.f;
        if(lane < d){
            s = edge_src[rs + lane];
            float t = ssrc[s] + sd;
            t = fmaxf(t, 0.2f*t);
            p = __expf(fminf(t, 80.f));
        }
        float sm = p;
        #pragma unroll
        for(int m=32;m>=1;m>>=1) sm += __shfl_xor(sm,m);
        float alpha = p * (1.0f/(sm + 1e-16f));
        lp[lane] = make_int2(__float_as_int(alpha), s);
        for(int i0=0; i0<d; i0+=8){
            int2 e0 = lp[i0 + grp];
            int2 e1 = lp[i0 + 4 + grp];
            float f0 = __int_as_float(e0.x);
            float f1 = __int_as_float(e1.x);
            uint2 k0 = ((const uint2*)(hb + ((size_t)e0.y<<6)))[ch];
            uint2 k1 = ((const uint2*)(hb + ((size_t)e1.y<<6)))[ch];
            a0 += f0*__uint_as_float(k0.x<<16);
            a1 += f0*__uint_as_float(k0.x&0xffff0000u);
            a2 += f0*__uint_as_float(k0.y<<16);
            a3 += f0*__uint_as_float(k0.y&0xffff0000u);
            a0 += f1*__uint_as_float(k1.x<<16);
            a1 += f1*__uint_as_float(k1.x&0xffff0000u);
            a2 += f1*__uint_as_float(k1.y<<16);
            a3 += f1*__uint_as_float(k1.y&0xffff0000u);
        }
    } else {
        float lmax = -1e30f;
        for(int j=lane; j<d; j+=64){
            int sj = edge_src[rs+j];
            float t = ssrc[sj] + sd;
            lmax = fmaxf(lmax, fmaxf(t, 0.2f*t));
        }
        #pragma unroll
        for(int m=32;m>=1;m>>=1) lmax = fmaxf(lmax, __shfl_xor(lmax,m));
        float lsum = 0.f;
        for(int j=lane; j<d; j+=64){
            int sj = edge_src[rs+j];
            float t = ssrc[sj] + sd;
            lsum += __expf(fmaxf(t, 0.2f*t) - lmax);
        }
        #pragma unroll
        for(int m=32;m>=1;m>>=1) lsum += __shfl_xor(lsum,m);
        float inv = 1.0f/(lsum + 1e-16f);
        for(int cb=0; cb<d; cb+=64){
            int s2 = 0; float al = 0.f;
            int j = cb + lane;
            if(j < d){
                s2 = edge_src[rs+j];
                float t = ssrc[s2] + sd;
                al = __expf(fmaxf(t, 0.2f*t) - lmax) * inv;
            }
            lp[lane] = make_int2(__float_as_int(al), s2);
            int dd = min(d - cb, 64);
            for(int i0=0; i0<dd; i0+=8){
                int2 e0 = lp[i0 + grp];
                int2 e1 = lp[i0 + 4 + grp];
                float f0 = __int_as_float(e0.x);
                float f1 = __int_as_float(e1.x);
                uint2 k0 = ((const uint2*)(hb + ((size_t)e0.y<<6)))[ch];
                uint2 k1 = ((const uint2*)(hb + ((size_t)e1.y<<6)))[ch];
                a0 += f0*__uint_as_float(k0.x<<16);
                a1 += f0*__uint_as_float(k0.x&0xffff0000u);
                a2 += f0*__uint_as_float(k0.y<<16);
                a3 += f0*__uint_as_float(k0.y&0xffff0000u);
                a0 += f1*__uint_as_float(k1.x<<16);
                a1 += f1*__uint_as_float(k1.x&0xffff0000u);
                a2 += f1*__uint_as_float(k1.y<<16);
                a3 += f1*__uint_as_float(k1.y&0xffff0000u);
            }
        }
    }

    a0 += __shfl_xor(a0,32); a1 += __shfl_xor(a1,32);
    a2 += __shfl_xor(a2,32); a3 += __shfl_xor(a3,32);
    a0 += __shfl_xor(a0,16); a1 += __shfl_xor(a1,16);
    a2 += __shfl_xor(a2,16); a3 += __shfl_xor(a3,16);

    float4 bv = ((const float4*)bias)[ch];
    if(LAYER == 1){
        if(lane < 16){
            float v0 = fast_tanh(a0 + bv.x);
            float v1 = fast_tanh(a1 + bv.y);
            float v2 = fast_tanh(a2 + bv.z);
            float v3 = fast_tanh(a3 + bv.w);
            uint2 o;
            o.x = (unsigned)bfbits(v0) | ((unsigned)bfbits(v1) << 16);
            o.y = (unsigned)bfbits(v2) | ((unsigned)bfbits(v3) << 16);
            ((uint2*)(out1b + ((size_t)wid<<6)))[ch] = o;
        }
    } else {
        float4 wv = ((const float4*)Wl)[ch];
        float r = (a0+bv.x)*wv.x + (a1+bv.y)*wv.y + (a2+bv.z)*wv.z + (a3+bv.w)*wv.w;
        r += __shfl_xor(r,8); r += __shfl_xor(r,4);
        r += __shfl_xor(r,2); r += __shfl_xor(r,1);
        if(lane == 0) outF[wid] = r + bl[0];
    }
}

// ---------------- launch ----------------
extern "C" void kernel_launch(void* const* d_in, const int* in_sizes, int n_in,
                              void* d_out, int out_size, void* d_ws, size_t ws_size,
                              hipStream_t stream) {
    const float* x   = (const float*)d_in[0];
    const int*   ei  = (const int*)d_in[1];
    const float* W1  = (const float*)d_in[2];
    const float* as1 = (const float*)d_in[3];
    const float* ad1 = (const float*)d_in[4];
    const float* b1  = (const float*)d_in[5];
    const float* W2  = (const float*)d_in[6];
    const float* as2 = (const float*)d_in[7];
    const float* ad2 = (const float*)d_in[8];
    const float* b2  = (const float*)d_in[9];
    const float* Wl  = (const float*)d_in[10];
    const float* bl  = (const float*)d_in[11];
    float* out = (float*)d_out;

    const int* srcp = ei;
    const int* dstp = ei + NE;

    char* w = (char*)d_ws;
    int*   edge_src = (int*)w;  w += (size_t)ET*4;      //  6.8 MB
    bf16*  hb       = (bf16*)w; w += (size_t)NN*64*2;   // 12.8 MB
    bf16*  t1b      = (bf16*)w; w += (size_t)NN*64*2;   // 12.8 MB
    int*   rowst    = (int*)w;  w += (size_t)NN*4;
    int*   deg      = (int*)w;  w += (size_t)NN*4;
    float* ssrc     = (float*)w; w += (size_t)NN*4;
    float* sdst     = (float*)w; w += (size_t)NN*4;
    int*   bcnt     = (int*)w;  w += (size_t)NB*BST*4;
    int*   binbuf   = (int*)hb;     // aliases hb: dead before k_gemm<1> writes

    const int nbBin = (ET + 2047)/2048;     // 831
    const int nbG   = 782;                  // 3128 waves -> ~2 tiles each
    const int nbA   = (NN + 3)/4;           // 25000

    hipMemsetAsync(bcnt, 0, (size_t)NB*BST*4, stream);
    k_bin  <<<nbBin, 256, 0, stream>>>(srcp, dstp, bcnt, binbuf);
    k_build<<<NB,    256, 0, stream>>>(bcnt, binbuf, edge_src, rowst, deg);

    // layer 1
    k_gemm<1><<<nbG, 256, 0, stream>>>((const void*)x, W1, as1, ad1, hb, ssrc, sdst);
    k_agg<1><<<nbA, 256, 0, stream>>>(rowst, deg, edge_src, ssrc, sdst, hb,
                                      b1, (const float*)nullptr, (const float*)nullptr,
                                      t1b, (float*)nullptr);
    // layer 2 + final linear
    k_gemm<0><<<nbG, 256, 0, stream>>>((const void*)t1b, W2, as2, ad2, hb, ssrc, sdst);
    k_agg<2><<<nbA, 256, 0, stream>>>(rowst, deg, edge_src, ssrc, sdst, hb,
                                      b2, Wl, bl,
                                      (bf16*)nullptr, out);
}

// Round 12
// 268.347 us; speedup vs baseline: 1.4788x; 1.0277x over previous
//
#include <hip/hip_runtime.h>
#include <hip/hip_bf16.h>

#define NN 100000
#define NE 1600000
#define ET (NE + NN)
#define NB 391          // buckets of 256 dst nodes
#define CAP 5120        // slots/bucket (mean 4352, +12 sigma)
#define BST 16          // bcnt pad: 64B per counter
#define NTILE (NN/16)   // 6250 gemm tiles

typedef __hip_bfloat16 bf16;
typedef __attribute__((ext_vector_type(8))) short short8;
typedef __attribute__((ext_vector_type(4))) float f32x4;

__device__ __forceinline__ unsigned short bfbits(float v){
    bf16 b = __float2bfloat16(v);
    return *(unsigned short*)&b;
}
__device__ __forceinline__ float lo16(unsigned u){ return __uint_as_float(u<<16); }
__device__ __forceinline__ float hi16(unsigned u){ return __uint_as_float(u&0xffff0000u); }
__device__ __forceinline__ float fast_tanh(float x){
    float e = __expf(2.f*x);
    return 1.f - __fdividef(2.f, e + 1.f);
}

// ---------------- CSR build: bin by dst>>8 ----------------
__global__ void __launch_bounds__(256) k_bin(const int* __restrict__ src,
        const int* __restrict__ dst, int* __restrict__ bcnt,
        int* __restrict__ binbuf){
    __shared__ int cnt[NB];
    __shared__ int cur[NB];
    int t = threadIdx.x;
    for(int i=t;i<NB;i+=256) cnt[i]=0;
    __syncthreads();
    int e0 = blockIdx.x*2048;
    #pragma unroll
    for(int k=0;k<8;k++){
        int e = e0 + k*256 + t;
        if(e < ET){ int d = (e < NE) ? dst[e] : (e - NE); atomicAdd(&cnt[d>>8], 1); }
    }
    __syncthreads();
    for(int i=t;i<NB;i+=256){ int c=cnt[i]; cur[i] = c ? atomicAdd(&bcnt[i*BST], c) : 0; }
    __syncthreads();
    #pragma unroll
    for(int k=0;k<8;k++){
        int e = e0 + k*256 + t;
        if(e < ET){
            int s, d;
            if(e < NE){ s = src[e]; d = dst[e]; } else { s = e - NE; d = s; }
            int b = d >> 8;
            int pos = atomicAdd(&cur[b], 1);
            if(pos < CAP) binbuf[b*CAP + pos] = (s << 8) | (d & 255);
        }
    }
}

// ---------------- CSR build: per-bucket dense build (base prefix fused) ----------------
__global__ void __launch_bounds__(256) k_build(const int* __restrict__ bcnt,
        const int* __restrict__ binbuf, int* __restrict__ edge_src,
        int* __restrict__ rowst, int* __restrict__ deg){
    __shared__ int lsrc[CAP];
    __shared__ int ldeg[256], lscan[256], lcur[256], red[256];
    int b = blockIdx.x, t = threadIdx.x;
    int cnt = min(bcnt[b*BST], CAP);
    int part = 0;
    for(int i=t;i<b;i+=256) part += min(bcnt[i*BST], CAP);
    red[t] = part; __syncthreads();
    for(int off=128; off>=1; off>>=1){ if(t<off) red[t]+=red[t+off]; __syncthreads(); }
    int base = red[0];
    __syncthreads();
    ldeg[t] = 0; __syncthreads();
    const int* bb = binbuf + b*CAP;
    for(int i=t;i<cnt;i+=256) atomicAdd(&ldeg[bb[i] & 255], 1);
    __syncthreads();
    int dv = ldeg[t]; lscan[t] = dv; __syncthreads();
    for(int off=1; off<256; off<<=1){
        int u = (t>=off) ? lscan[t-off] : 0;
        __syncthreads(); lscan[t] += u; __syncthreads();
    }
    int excl = lscan[t] - dv; lcur[t] = excl;
    int node = b*256 + t;
    if(node < NN){ rowst[node] = base + excl; deg[node] = dv; }
    __syncthreads();
    for(int i=t;i<cnt;i+=256){
        int ent = bb[i];
        int pos = atomicAdd(&lcur[ent & 255], 1);
        lsrc[pos] = ent >> 8;
    }
    __syncthreads();
    for(int i=t;i<cnt;i+=256) edge_src[base+i] = lsrc[i];
}

// ---------------- h = x@W via MFMA, s_src, s_dst ----------------
// One 16-node tile per wave-iteration. A-frag loaded straight from global
// (lane m=lane&15 reads x[n0+m][kh*32+q*8..+7]); W held as 8 short8 B-frags.
// D layout: col=lane&15, row=(lane>>4)*4+reg (verified round 10).

template<int FPIN>
__global__ void __launch_bounds__(256) k_gemm(const void* __restrict__ xin,
        const float* __restrict__ W, const float* __restrict__ avs,
        const float* __restrict__ avd, bf16* __restrict__ hb,
        float* __restrict__ ssrc, float* __restrict__ sdst){
    int tid = threadIdx.x, lane = tid & 63;
    int col = lane & 15, q = lane >> 4;
    short8 Bf[2][4];
    #pragma unroll
    for(int kh=0;kh<2;kh++){
        #pragma unroll
        for(int nb=0;nb<4;nb++){
            short8 b;
            #pragma unroll
            for(int j=0;j<8;j++){
                float w = W[(kh*32 + q*8 + j)*64 + nb*16 + col];
                b[j] = (short)bfbits(w);
            }
            Bf[kh][nb] = b;
        }
    }
    float as[4], ad[4];
    #pragma unroll
    for(int nb=0;nb<4;nb++){ as[nb] = avs[nb*16+col]; ad[nb] = avd[nb*16+col]; }

    int gw = (blockIdx.x*256 + tid) >> 6;
    int nwaves = gridDim.x*4;
    for(int tile = gw; tile < NTILE; tile += nwaves){
        int n0 = tile*16;
        f32x4 acc[4];
        #pragma unroll
        for(int nb=0;nb<4;nb++) acc[nb] = (f32x4){0.f,0.f,0.f,0.f};
        #pragma unroll
        for(int kh=0;kh<2;kh++){
            short8 a;
            if(FPIN){
                const float4* xr = (const float4*)((const float*)xin
                                    + (size_t)(n0+col)*64 + kh*32 + q*8);
                float4 u = xr[0], v = xr[1];
                a[0]=(short)bfbits(u.x); a[1]=(short)bfbits(u.y);
                a[2]=(short)bfbits(u.z); a[3]=(short)bfbits(u.w);
                a[4]=(short)bfbits(v.x); a[5]=(short)bfbits(v.y);
                a[6]=(short)bfbits(v.z); a[7]=(short)bfbits(v.w);
            } else {
                a = *(const short8*)((const bf16*)xin
                                    + (size_t)(n0+col)*64 + kh*32 + q*8);
            }
            #pragma unroll
            for(int nb=0;nb<4;nb++)
                acc[nb] = __builtin_amdgcn_mfma_f32_16x16x32_bf16(a, Bf[kh][nb], acc[nb], 0,0,0);
        }
        #pragma unroll
        for(int nb=0;nb<4;nb++){
            #pragma unroll
            for(int r=0;r<4;r++)
                hb[(size_t)(n0 + q*4 + r)*64 + nb*16 + col] = __float2bfloat16(acc[nb][r]);
        }
        #pragma unroll
        for(int r=0;r<4;r++){
            float ps = acc[0][r]*as[0] + acc[1][r]*as[1] + acc[2][r]*as[2] + acc[3][r]*as[3];
            float pd = acc[0][r]*ad[0] + acc[1][r]*ad[1] + acc[2][r]*ad[2] + acc[3][r]*ad[3];
            #pragma unroll
            for(int m=8;m>=1;m>>=1){ ps += __shfl_xor(ps,m); pd += __shfl_xor(pd,m); }
            if(col == 0){ ssrc[n0 + q*4 + r] = ps; sdst[n0 + q*4 + r] = pd; }
        }
    }
}

// ---------------- attention + aggregation ----------------
// wave per dst node; 16B/lane gather: uint4 = 8 channels, 8 lanes cover a
// 128B row, 16 edges per iteration (2 loads in flight). LDS (alpha,src) table.

template<int LAYER>
__global__ void __launch_bounds__(256) k_agg(
        const int* __restrict__ rowst, const int* __restrict__ deg,
        const int* __restrict__ edge_src,
        const float* __restrict__ ssrc, const float* __restrict__ sdst,
        const bf16* __restrict__ hb,
        const float* __restrict__ bias, const float* __restrict__ Wl,
        const float* __restrict__ bl,
        bf16* __restrict__ out1b, float* __restrict__ outF){
    __shared__ int2 pairs[256];
    int tid = threadIdx.x;
    int wid  = (blockIdx.x*256 + tid) >> 6;
    int lane = tid & 63;
    if(wid >= NN) return;
    int2* lp = pairs + (tid & 192);      // wave-private 64-entry table
    int rs = rowst[wid];
    int d  = deg[wid];
    float sd = sdst[wid];
    int g8 = lane >> 3;                  // row-group 0..7
    int c  = lane & 7;                   // channel chunk: channels c*8..c*8+7
    float a0=0.f,a1=0.f,a2=0.f,a3=0.f,a4=0.f,a5=0.f,a6=0.f,a7=0.f;

    if(d <= 64){
        int s = 0; float pr = 0.f;
        if(lane < d){
            s = edge_src[rs + lane];
            float t = ssrc[s] + sd;
            t = fmaxf(t, 0.2f*t);            // leaky_relu
            pr = __expf(fminf(t, 80.f));     // no max-shift: logits O(10)
        }
        float sm = pr;
        #pragma unroll
        for(int m=32;m>=1;m>>=1) sm += __shfl_xor(sm,m);
        float alpha = pr * (1.0f/(sm + 1e-16f));
        lp[lane] = make_int2(__float_as_int(alpha), s);   // lanes>=d: alpha=0
        for(int i0=0; i0<d; i0+=16){
            int2 e0 = lp[i0 + g8];
            int2 e1 = lp[i0 + 8 + g8];
            float f0 = __int_as_float(e0.x);
            float f1 = __int_as_float(e1.x);
            uint4 k0 = *(const uint4*)(hb + ((size_t)e0.y<<6) + (c<<3));
            uint4 k1 = *(const uint4*)(hb + ((size_t)e1.y<<6) + (c<<3));
            a0 += f0*lo16(k0.x); a1 += f0*hi16(k0.x);
            a2 += f0*lo16(k0.y); a3 += f0*hi16(k0.y);
            a4 += f0*lo16(k0.z); a5 += f0*hi16(k0.z);
            a6 += f0*lo16(k0.w); a7 += f0*hi16(k0.w);
            a0 += f1*lo16(k1.x); a1 += f1*hi16(k1.x);
            a2 += f1*lo16(k1.y); a3 += f1*hi16(k1.y);
            a4 += f1*lo16(k1.z); a5 += f1*hi16(k1.z);
            a6 += f1*lo16(k1.w); a7 += f1*hi16(k1.w);
        }
    } else {
        // generic path (d>64): keep max-shift for safety
        float lmax = -1e30f;
        for(int j=lane; j<d; j+=64){
            int sj = edge_src[rs+j];
            float t = ssrc[sj] + sd;
            lmax = fmaxf(lmax, fmaxf(t, 0.2f*t));
        }
        #pragma unroll
        for(int m=32;m>=1;m>>=1) lmax = fmaxf(lmax, __shfl_xor(lmax,m));
        float lsum = 0.f;
        for(int j=lane; j<d; j+=64){
            int sj = edge_src[rs+j];
            float t = ssrc[sj] + sd;
            lsum += __expf(fmaxf(t, 0.2f*t) - lmax);
        }
        #pragma unroll
        for(int m=32;m>=1;m>>=1) lsum += __shfl_xor(lsum,m);
        float inv = 1.0f/(lsum + 1e-16f);
        for(int cb=0; cb<d; cb+=64){
            int s2 = 0; float al = 0.f;
            int j = cb + lane;
            if(j < d){
                s2 = edge_src[rs+j];
                float t = ssrc[s2] + sd;
                al = __expf(fmaxf(t, 0.2f*t) - lmax) * inv;
            }
            lp[lane] = make_int2(__float_as_int(al), s2);
            int dd = min(d - cb, 64);
            for(int i0=0; i0<dd; i0+=16){
                int2 e0 = lp[i0 + g8];
                int2 e1 = lp[i0 + 8 + g8];
                float f0 = __int_as_float(e0.x);
                float f1 = __int_as_float(e1.x);
                uint4 k0 = *(const uint4*)(hb + ((size_t)e0.y<<6) + (c<<3));
                uint4 k1 = *(const uint4*)(hb + ((size_t)e1.y<<6) + (c<<3));
                a0 += f0*lo16(k0.x); a1 += f0*hi16(k0.x);
                a2 += f0*lo16(k0.y); a3 += f0*hi16(k0.y);
                a4 += f0*lo16(k0.z); a5 += f0*hi16(k0.z);
                a6 += f0*lo16(k0.w); a7 += f0*hi16(k0.w);
                a0 += f1*lo16(k1.x); a1 += f1*hi16(k1.x);
                a2 += f1*lo16(k1.y); a3 += f1*hi16(k1.y);
                a4 += f1*lo16(k1.z); a5 += f1*hi16(k1.z);
                a6 += f1*lo16(k1.w); a7 += f1*hi16(k1.w);
            }
        }
    }

    // fold over the 8 row-groups (lane bits 3..5)
    #pragma unroll
    for(int m=32;m>=8;m>>=1){
        a0 += __shfl_xor(a0,m); a1 += __shfl_xor(a1,m);
        a2 += __shfl_xor(a2,m); a3 += __shfl_xor(a3,m);
        a4 += __shfl_xor(a4,m); a5 += __shfl_xor(a5,m);
        a6 += __shfl_xor(a6,m); a7 += __shfl_xor(a7,m);
    }

    const float4* bp = (const float4*)bias;
    float4 bv0 = bp[c*2], bv1 = bp[c*2+1];
    if(LAYER == 1){
        if(g8 == 0){
            uint4 o;
            o.x = (unsigned)bfbits(fast_tanh(a0+bv0.x)) | ((unsigned)bfbits(fast_tanh(a1+bv0.y))<<16);
            o.y = (unsigned)bfbits(fast_tanh(a2+bv0.z)) | ((unsigned)bfbits(fast_tanh(a3+bv0.w))<<16);
            o.z = (unsigned)bfbits(fast_tanh(a4+bv1.x)) | ((unsigned)bfbits(fast_tanh(a5+bv1.y))<<16);
            o.w = (unsigned)bfbits(fast_tanh(a6+bv1.z)) | ((unsigned)bfbits(fast_tanh(a7+bv1.w))<<16);
            *(uint4*)(out1b + ((size_t)wid<<6) + (c<<3)) = o;
        }
    } else {
        const float4* wp = (const float4*)Wl;
        float4 wv0 = wp[c*2], wv1 = wp[c*2+1];
        float r = (a0+bv0.x)*wv0.x + (a1+bv0.y)*wv0.y + (a2+bv0.z)*wv0.z + (a3+bv0.w)*wv0.w
                + (a4+bv1.x)*wv1.x + (a5+bv1.y)*wv1.y + (a6+bv1.z)*wv1.z + (a7+bv1.w)*wv1.w;
        r += __shfl_xor(r,1); r += __shfl_xor(r,2); r += __shfl_xor(r,4);
        if(lane == 0) outF[wid] = r + bl[0];
    }
}

// ---------------- launch ----------------
extern "C" void kernel_launch(void* const* d_in, const int* in_sizes, int n_in,
                              void* d_out, int out_size, void* d_ws, size_t ws_size,
                              hipStream_t stream) {
    const float* x   = (const float*)d_in[0];
    const int*   ei  = (const int*)d_in[1];
    const float* W1  = (const float*)d_in[2];
    const float* as1 = (const float*)d_in[3];
    const float* ad1 = (const float*)d_in[4];
    const float* b1  = (const float*)d_in[5];
    const float* W2  = (const float*)d_in[6];
    const float* as2 = (const float*)d_in[7];
    const float* ad2 = (const float*)d_in[8];
    const float* b2  = (const float*)d_in[9];
    const float* Wl  = (const float*)d_in[10];
    const float* bl  = (const float*)d_in[11];
    float* out = (float*)d_out;

    const int* srcp = ei;
    const int* dstp = ei + NE;

    char* w = (char*)d_ws;
    int*   edge_src = (int*)w;  w += (size_t)ET*4;      //  6.8 MB
    bf16*  hb       = (bf16*)w; w += (size_t)NN*64*2;   // 12.8 MB
    bf16*  t1b      = (bf16*)w; w += (size_t)NN*64*2;   // 12.8 MB
    int*   rowst    = (int*)w;  w += (size_t)NN*4;
    int*   deg      = (int*)w;  w += (size_t)NN*4;
    float* ssrc     = (float*)w; w += (size_t)NN*4;
    float* sdst     = (float*)w; w += (size_t)NN*4;
    int*   bcnt     = (int*)w;  w += (size_t)NB*BST*4;
    int*   binbuf   = (int*)hb;     // aliases hb: dead before k_gemm<1> writes

    const int nbBin = (ET + 2047)/2048;     // 831
    const int nbG   = 782;                  // 3128 waves -> ~2 tiles each
    const int nbA   = (NN + 3)/4;           // 25000

    hipMemsetAsync(bcnt, 0, (size_t)NB*BST*4, stream);
    k_bin  <<<nbBin, 256, 0, stream>>>(srcp, dstp, bcnt, binbuf);
    k_build<<<NB,    256, 0, stream>>>(bcnt, binbuf, edge_src, rowst, deg);

    // layer 1
    k_gemm<1><<<nbG, 256, 0, stream>>>((const void*)x, W1, as1, ad1, hb, ssrc, sdst);
    k_agg<1><<<nbA, 256, 0, stream>>>(rowst, deg, edge_src, ssrc, sdst, hb,
                                      b1, (const float*)nullptr, (const float*)nullptr,
                                      t1b, (float*)nullptr);
    // layer 2 + final linear
    k_gemm<0><<<nbG, 256, 0, stream>>>((const void*)t1b, W2, as2, ad2, hb, ssrc, sdst);
    k_agg<2><<<nbA, 256, 0, stream>>>(rowst, deg, edge_src, ssrc, sdst, hb,
                                      b2, Wl, bl,
                                      (bf16*)nullptr, out);
}